// Round 9
// baseline (248.990 us; speedup 1.0000x reference)
//
#include <hip/hip_runtime.h>
#include <hip/hip_bf16.h>
#include <stdint.h>

// Problem constants
#define Bsz 4
#define Tsz 2048
#define Csz 1024
#define Hn  16
#define Dh  64
#define BH  (Bsz*Hn)      // 64
#define Mrows (Bsz*Tsz)   // 8192
#define N1  (3*Csz)       // 3072

typedef short s16x8 __attribute__((ext_vector_type(8)));
typedef short s16x4 __attribute__((ext_vector_type(4)));
typedef float fx4   __attribute__((ext_vector_type(4)));

static __device__ __forceinline__ short f2bf(float x) {
  __hip_bfloat16 h = __float2bfloat16(x);   // RNE
  return __builtin_bit_cast(short, h);
}

#define GLDS16(g, l) __builtin_amdgcn_global_load_lds( \
    (const __attribute__((address_space(1))) void*)(g), \
    (__attribute__((address_space(3))) void*)(l), 16, 0, 0)

#define WAITV(n) __asm__ __volatile__("s_waitcnt vmcnt(" #n ")" ::: "memory")
#define LGKM0    __asm__ __volatile__("s_waitcnt lgkmcnt(0)" ::: "memory")
#define SCHEDB   __builtin_amdgcn_sched_barrier(0)
#define BAR      __builtin_amdgcn_s_barrier()

// ---------- fused prep: f32->bf16 cvt + two weight transposes -------------
__global__ __launch_bounds__(256) void prep_kernel(
    const float* __restrict__ x,  short* __restrict__ xb,
    const float* __restrict__ wq, short* __restrict__ wqT,
    const float* __restrict__ wp, short* __restrict__ wpT)
{
  const int bid = (int)blockIdx.x;
  if (bid < 1024) {
    const int n4 = Mrows*Csz/4;
    int i = bid * 256 + threadIdx.x;
    const int stride = 1024 * 256;
    for (; i < n4; i += stride) {
      float4 v = ((const float4*)x)[i];
      s16x4 o;
      o.x = f2bf(v.x); o.y = f2bf(v.y); o.z = f2bf(v.z); o.w = f2bf(v.w);
      ((s16x4*)xb)[i] = o;
    }
    return;
  }
  const float* w; short* wt; int K, N, tb;
  if (bid < 1024 + 3072) { w = wq; wt = wqT; K = Csz; N = N1;  tb = bid - 1024; }
  else                   { w = wp; wt = wpT; K = Csz; N = Csz; tb = bid - 4096; }
  const int nbx = N >> 5;
  const int n0 = (tb % nbx) * 32;
  const int k0 = (tb / nbx) * 32;
  __shared__ float tile[32][33];
  int tc = threadIdx.x & 31;
  int tr = threadIdx.x >> 5;      // 0..7
#pragma unroll
  for (int p = 0; p < 4; p++) {
    int r = tr + p*8;
    tile[r][tc] = w[(size_t)(k0 + r) * N + (n0 + tc)];
  }
  __syncthreads();
#pragma unroll
  for (int p = 0; p < 4; p++) {
    int r = tr + p*8;   // output (n) row
    wt[(size_t)(n0 + r) * K + (k0 + tc)] = f2bf(tile[tc][r]);
  }
}

static __device__ __forceinline__ s16x8 lds_frag(const short* p, int off) {
  return *(const s16x8*)(p + off);
}

// ============ QKV GEMM: 256x256, BK=64, 8-phase (R15: hazard-fixed) =======
// R13's bug: SA(Tp,h0) staged at P2 overwrote even-A rows 64..127 which
// wm=0 waves read at P3 (fragment halves are per-wave 64-row slices of a
// 128-row band, NOT the 128-row staging halves). Corrected placement honors
// "all reads of region X strictly precede X's re-stage, barrier-separated":
//   even-A reads span P1-P3, even-B P1-P2, odd-A P5-P7, odd-B P5-P6.
//   P1:SB(T1,h1) P2:SA(T1,h1) P3:SB(Tp,h0) P4:SB(Tp,h1)
//   P5:SA(Tp,h0) P6:SA(Tp,h1) P7:SB(Tq,h0) P8:SA(Tq,h0)
// Ledger: carried-in 4 {SB(o,h0),SA(o,h0)}; P4 outstanding 12 -> vmcnt(4)
// retires tile T1's 8; P8 outstanding 12 -> vmcnt(4) retires tile Tp's 8.
// Prologue: tile0 (8) + SB(1,h0),SA(1,h0) -> vmcnt(4). Tail: Tp>=NT -> P4
// vmcnt(0); (Tp<NT && Tq>=NT) impossible for even NT. Quadrant rotation,
// swizzle (slot ^= row&7, both-sides), epilogue unchanged from R13.
__global__ __launch_bounds__(512) void gemm_qkv_kernel(
    const short* __restrict__ A, const short* __restrict__ Bt,
    short* __restrict__ Qo, short* __restrict__ Ko, short* __restrict__ Vo,
    int Ndim, int Kdim)
{
  __shared__ __align__(16) short sA[2*16384];   // 2 x 32 KB
  __shared__ __align__(16) short sB[2*16384];   // 2 x 32 KB
  const int tid  = threadIdx.x;
  const int lane = tid & 63;
  const int lr   = lane & 15;
  const int lq   = lane >> 4;
  const int wv   = tid >> 6;               // 0..7
  const int wm   = wv >> 2;                // 0..1
  const int wn   = wv & 3;                 // 0..3
  const int nb   = Ndim >> 8;
  const int nwg  = (int)gridDim.x;
  const int orig = (int)blockIdx.x;
  const int wgid = (orig & 7) * (nwg >> 3) + (orig >> 3);
  const int bm   = wgid / nb;
  const int bn   = wgid % nb;

  const short* Ab = A  + (size_t)bm * 256 * Kdim;
  const short* Bb = Bt + (size_t)bn * 256 * Kdim;

  // stage sources: chunk c in a half = (row_local = c>>3, slot = c&7);
  // source k-chunk = slot ^ (row&7); LDS dest linear (c*16B).
  const short* gAs[2];
  const short* gBs[2];
  int ldso[2];
#pragma unroll
  for (int j = 0; j < 2; j++) {
    int c = tid + 512*j, r = c >> 3, sl = ((c & 7) ^ (r & 7)) * 8;
    gAs[j] = Ab + (size_t)r * Kdim + sl;
    gBs[j] = Bb + (size_t)r * Kdim + sl;
    ldso[j] = c * 8;
  }

  auto SA = [&](int t, int h) {
#pragma unroll
    for (int j = 0; j < 2; j++)
      GLDS16(gAs[j] + (size_t)(h*128)*Kdim + t*64, sA + (t&1)*16384 + h*8192 + ldso[j]);
  };
  auto SB = [&](int t, int h) {
#pragma unroll
    for (int j = 0; j < 2; j++)
      GLDS16(gBs[j] + (size_t)(h*128)*Kdim + t*64, sB + (t&1)*16384 + h*8192 + ldso[j]);
  };

  // fragment offsets (shorts) within one tile buffer [256][64]
  int offA[8][2], offB[4][2];
#pragma unroll
  for (int mt = 0; mt < 8; mt++)
#pragma unroll
    for (int kk = 0; kk < 2; kk++) {
      int row = wm*128 + mt*16 + lr;
      offA[mt][kk] = row*64 + ((((kk<<2)|lq) ^ (row & 7)) << 3);
    }
#pragma unroll
  for (int nt = 0; nt < 4; nt++)
#pragma unroll
    for (int kk = 0; kk < 2; kk++) {
      int row = wn*64 + nt*16 + lr;
      offB[nt][kk] = row*64 + ((((kk<<2)|lq) ^ (row & 7)) << 3);
    }

  fx4 acc[8][4];
#pragma unroll
  for (int i = 0; i < 8; i++)
#pragma unroll
    for (int j = 0; j < 4; j++) acc[i][j] = (fx4){0.f, 0.f, 0.f, 0.f};

  const int NT = Kdim >> 6;   // K-tiles of 64 (16 for K=1024); even, >=2

  // prologue: tile 0 (8 loads) + SB(1,h0), SA(1,h0) (4); vmcnt(4) retires
  // exactly tile 0's 8.
  SA(0,0); SA(0,1); SB(0,0); SB(0,1);
  SB(1,0); SA(1,0);
  WAITV(4);
  BAR; SCHEDB;

  for (int i = 0; i < NT/2; ++i) {
    const int T1 = 2*i+1, Tp = 2*i+2, Tq = 2*i+3;
    const short* bA0 = sA;            const short* bB0 = sB;
    const short* bA1 = sA + 16384;    const short* bB1 = sB + 16384;
    s16x8 afr[4][2], bf0[2][2], bf1[2][2];

    // ---------------- tile T0 (even slot) ----------------
    // P1: read A frags 0-3 + B frags 0-1; stage SB(T1,h1); MFMA Q(0,0)
#pragma unroll
    for (int m = 0; m < 4; m++)
#pragma unroll
      for (int k = 0; k < 2; k++) afr[m][k] = lds_frag(bA0, offA[m][k]);
#pragma unroll
    for (int n = 0; n < 2; n++)
#pragma unroll
      for (int k = 0; k < 2; k++) bf0[n][k] = lds_frag(bB0, offB[n][k]);
    SB(T1, 1);
    BAR; LGKM0; SCHEDB;
    __builtin_amdgcn_s_setprio(1);
#pragma unroll
    for (int k = 0; k < 2; k++)
#pragma unroll
      for (int m = 0; m < 4; m++) {
        acc[m][0] = __builtin_amdgcn_mfma_f32_16x16x32_bf16(afr[m][k], bf0[0][k], acc[m][0], 0, 0, 0);
        acc[m][1] = __builtin_amdgcn_mfma_f32_16x16x32_bf16(afr[m][k], bf0[1][k], acc[m][1], 0, 0, 0);
      }
    __builtin_amdgcn_s_setprio(0);
    SCHEDB; BAR;

    // P2: read B frags 2-3; stage SA(T1,h1); MFMA Q(0,1)
#pragma unroll
    for (int n = 0; n < 2; n++)
#pragma unroll
      for (int k = 0; k < 2; k++) bf1[n][k] = lds_frag(bB0, offB[n+2][k]);
    SA(T1, 1);
    BAR; LGKM0; SCHEDB;
    __builtin_amdgcn_s_setprio(1);
#pragma unroll
    for (int k = 0; k < 2; k++)
#pragma unroll
      for (int m = 0; m < 4; m++) {
        acc[m][2] = __builtin_amdgcn_mfma_f32_16x16x32_bf16(afr[m][k], bf1[0][k], acc[m][2], 0, 0, 0);
        acc[m][3] = __builtin_amdgcn_mfma_f32_16x16x32_bf16(afr[m][k], bf1[1][k], acc[m][3], 0, 0, 0);
      }
    __builtin_amdgcn_s_setprio(0);
    SCHEDB; BAR;

    // P3: read A frags 4-7 (last even-A readers); stage SB(Tp,h0); MFMA Q(1,1)
#pragma unroll
    for (int m = 0; m < 4; m++)
#pragma unroll
      for (int k = 0; k < 2; k++) afr[m][k] = lds_frag(bA0, offA[m+4][k]);
    if (Tp < NT) SB(Tp, 0);
    BAR; LGKM0; SCHEDB;
    __builtin_amdgcn_s_setprio(1);
#pragma unroll
    for (int k = 0; k < 2; k++)
#pragma unroll
      for (int m = 0; m < 4; m++) {
        acc[m+4][2] = __builtin_amdgcn_mfma_f32_16x16x32_bf16(afr[m][k], bf1[0][k], acc[m+4][2], 0, 0, 0);
        acc[m+4][3] = __builtin_amdgcn_mfma_f32_16x16x32_bf16(afr[m][k], bf1[1][k], acc[m+4][3], 0, 0, 0);
      }
    __builtin_amdgcn_s_setprio(0);
    SCHEDB; BAR;

    // P4: no reads; stage SB(Tp,h1); MFMA Q(1,0); vmcnt(4) -> tile T1 ready
    if (Tp < NT) SB(Tp, 1);
    BAR; SCHEDB;
    __builtin_amdgcn_s_setprio(1);
#pragma unroll
    for (int k = 0; k < 2; k++)
#pragma unroll
      for (int m = 0; m < 4; m++) {
        acc[m+4][0] = __builtin_amdgcn_mfma_f32_16x16x32_bf16(afr[m][k], bf0[0][k], acc[m+4][0], 0, 0, 0);
        acc[m+4][1] = __builtin_amdgcn_mfma_f32_16x16x32_bf16(afr[m][k], bf0[1][k], acc[m+4][1], 0, 0, 0);
      }
    __builtin_amdgcn_s_setprio(0);
    SCHEDB;
    if (Tp < NT) { WAITV(4); } else { WAITV(0); }
    BAR; SCHEDB;

    // ---------------- tile T1 (odd slot) ----------------
    // P5: read A frags 0-3 + B frags 0-1; stage SA(Tp,h0); MFMA Q(0,0)
#pragma unroll
    for (int m = 0; m < 4; m++)
#pragma unroll
      for (int k = 0; k < 2; k++) afr[m][k] = lds_frag(bA1, offA[m][k]);
#pragma unroll
    for (int n = 0; n < 2; n++)
#pragma unroll
      for (int k = 0; k < 2; k++) bf0[n][k] = lds_frag(bB1, offB[n][k]);
    if (Tp < NT) SA(Tp, 0);
    BAR; LGKM0; SCHEDB;
    __builtin_amdgcn_s_setprio(1);
#pragma unroll
    for (int k = 0; k < 2; k++)
#pragma unroll
      for (int m = 0; m < 4; m++) {
        acc[m][0] = __builtin_amdgcn_mfma_f32_16x16x32_bf16(afr[m][k], bf0[0][k], acc[m][0], 0, 0, 0);
        acc[m][1] = __builtin_amdgcn_mfma_f32_16x16x32_bf16(afr[m][k], bf0[1][k], acc[m][1], 0, 0, 0);
      }
    __builtin_amdgcn_s_setprio(0);
    SCHEDB; BAR;

    // P6: read B frags 2-3 (last odd-B readers); stage SA(Tp,h1); MFMA Q(0,1)
#pragma unroll
    for (int n = 0; n < 2; n++)
#pragma unroll
      for (int k = 0; k < 2; k++) bf1[n][k] = lds_frag(bB1, offB[n+2][k]);
    if (Tp < NT) SA(Tp, 1);
    BAR; LGKM0; SCHEDB;
    __builtin_amdgcn_s_setprio(1);
#pragma unroll
    for (int k = 0; k < 2; k++)
#pragma unroll
      for (int m = 0; m < 4; m++) {
        acc[m][2] = __builtin_amdgcn_mfma_f32_16x16x32_bf16(afr[m][k], bf1[0][k], acc[m][2], 0, 0, 0);
        acc[m][3] = __builtin_amdgcn_mfma_f32_16x16x32_bf16(afr[m][k], bf1[1][k], acc[m][3], 0, 0, 0);
      }
    __builtin_amdgcn_s_setprio(0);
    SCHEDB; BAR;

    // P7: read A frags 4-7 (last odd-A readers); stage SB(Tq,h0); MFMA Q(1,1)
#pragma unroll
    for (int m = 0; m < 4; m++)
#pragma unroll
      for (int k = 0; k < 2; k++) afr[m][k] = lds_frag(bA1, offA[m+4][k]);
    if (Tq < NT) SB(Tq, 0);
    BAR; LGKM0; SCHEDB;
    __builtin_amdgcn_s_setprio(1);
#pragma unroll
    for (int k = 0; k < 2; k++)
#pragma unroll
      for (int m = 0; m < 4; m++) {
        acc[m+4][2] = __builtin_amdgcn_mfma_f32_16x16x32_bf16(afr[m][k], bf1[0][k], acc[m+4][2], 0, 0, 0);
        acc[m+4][3] = __builtin_amdgcn_mfma_f32_16x16x32_bf16(afr[m][k], bf1[1][k], acc[m+4][3], 0, 0, 0);
      }
    __builtin_amdgcn_s_setprio(0);
    SCHEDB; BAR;

    // P8: no reads; stage SA(Tq,h0); MFMA Q(1,0); vmcnt(4) -> tile Tp ready
    if (Tq < NT) SA(Tq, 0);
    BAR; SCHEDB;
    __builtin_amdgcn_s_setprio(1);
#pragma unroll
    for (int k = 0; k < 2; k++)
#pragma unroll
      for (int m = 0; m < 4; m++) {
        acc[m+4][0] = __builtin_amdgcn_mfma_f32_16x16x32_bf16(afr[m][k], bf0[0][k], acc[m+4][0], 0, 0, 0);
        acc[m+4][1] = __builtin_amdgcn_mfma_f32_16x16x32_bf16(afr[m][k], bf0[1][k], acc[m+4][1], 0, 0, 0);
      }
    __builtin_amdgcn_s_setprio(0);
    SCHEDB;
    if (Tq < NT) { WAITV(4); }
    BAR; SCHEDB;
  }

  // epilogue: Q/K/V scatter
  const int gm0 = bm*256 + wm*128;
  const int gn0 = bn*256 + wn*64;
#pragma unroll
  for (int mt = 0; mt < 8; mt++)
#pragma unroll
    for (int nt = 0; nt < 4; nt++) {
      int n   = gn0 + nt*16 + lr;
      int sec = n >> 10;        // 0=q 1=k 2=v (uniform per nt)
      int cc  = n & 1023;
      int hh  = cc >> 6;
      int dd  = cc & 63;
      if (sec == 2) {
        int tt0 = gm0 + mt*16 + lq*4;
        int bb  = tt0 >> 11;
        int bh  = bb * Hn + hh;
        s16x4 pk;
        pk.x = f2bf(acc[mt][nt][0]); pk.y = f2bf(acc[mt][nt][1]);
        pk.z = f2bf(acc[mt][nt][2]); pk.w = f2bf(acc[mt][nt][3]);
        *(s16x4*)(Vo + ((size_t)bh * Dh + dd) * Tsz + (tt0 & 2047)) = pk;
      } else {
#pragma unroll
        for (int r = 0; r < 4; r++) {
          int m  = gm0 + mt*16 + lq*4 + r;
          int bb = m >> 11;
          int tt = m & 2047;
          int bh = bb * Hn + hh;
          short v = f2bf(acc[mt][nt][r]);
          if (sec == 0) Qo[((size_t)bh * Tsz + tt) * Dh + dd] = v;
          else          Ko[((size_t)bh * Tsz + tt) * Dh + dd] = v;
        }
      }
    }
}

// ============ proj GEMM: 128x256 tile, BK=64 (R12 anchor, verbatim) =======
__global__ __launch_bounds__(512) void gemm_bt_kernel(
    const short* __restrict__ A, const short* __restrict__ Bt,
    float* __restrict__ Cf, int Mdim, int Ndim, int Kdim)
{
  __shared__ __align__(16) short sA[3][128*64];   // 3 x 16 KB
  __shared__ __align__(16) short sB[3][256*64];   // 3 x 32 KB
  const int tid  = threadIdx.x;
  const int lane = tid & 63;
  const int lr   = lane & 15;
  const int lq   = lane >> 4;
  const int wv   = tid >> 6;               // 0..7
  const int nb   = Ndim >> 8;              // 256-wide n tiles
  const int nwg  = (int)gridDim.x;
  const int orig = (int)blockIdx.x;
  const int wgid = (orig & 7) * (nwg >> 3) + (orig >> 3);
  const int bm   = wgid / nb;
  const int bn   = wgid % nb;
  const int m_off = (wv & 1) << 6;         // 0 / 64
  const int n_off = (wv >> 1) << 6;        // 0 / 64 / 128 / 192

  const short* Ab = A  + (size_t)bm * 128 * Kdim;
  const short* Bb = Bt + (size_t)bn * 256 * Kdim;

  const short* gA[2];
  const short* gB[4];
#pragma unroll
  for (int j = 0; j < 2; j++) {
    int c = tid + 512*j, r = c >> 3, o = ((c & 7) ^ (r & 7)) * 8;
    gA[j] = Ab + (size_t)r * Kdim + o;
  }
#pragma unroll
  for (int j = 0; j < 4; j++) {
    int c = tid + 512*j, r = c >> 3, o = ((c & 7) ^ (r & 7)) * 8;
    gB[j] = Bb + (size_t)r * Kdim + o;
  }

  int offA[4][2], offB[4][2];
#pragma unroll
  for (int ft = 0; ft < 4; ft++)
#pragma unroll
    for (int kk = 0; kk < 2; kk++) {
      int ra = m_off + ft*16 + lr;
      offA[ft][kk] = ra*64 + ((((kk<<2) | lq) ^ (ra & 7)) << 3);
      int rb = n_off + ft*16 + lr;
      offB[ft][kk] = rb*64 + ((((kk<<2) | lq) ^ (rb & 7)) << 3);
    }

  fx4 acc[4][4];
#pragma unroll
  for (int i = 0; i < 4; i++)
#pragma unroll
    for (int j = 0; j < 4; j++) acc[i][j] = (fx4){0.f, 0.f, 0.f, 0.f};

  auto STAGE_P1 = [&](int k0, short* dA, short* dB) {   // 3 loads
    GLDS16(gA[0] + k0, dA + tid*8);
    GLDS16(gA[1] + k0, dA + (tid+512)*8);
    GLDS16(gB[0] + k0, dB + tid*8);
  };
  auto STAGE_P2 = [&](int k0, short* dB) {              // 3 loads
    GLDS16(gB[1] + k0, dB + (tid+512)*8);
    GLDS16(gB[2] + k0, dB + (tid+1024)*8);
    GLDS16(gB[3] + k0, dB + (tid+1536)*8);
  };

  const int NIT = Kdim >> 6;   // K-tiles of 64 (16 for K=1024)

  STAGE_P1(0,  sA[0], sB[0]); STAGE_P2(0,  sB[0]);
  STAGE_P1(64, sA[1], sB[1]); STAGE_P2(64, sB[1]);
  WAITV(6);
  BAR;

  const short *cA = sA[0], *cB = sB[0];
  const short *nA = sA[1], *nB = sB[1];
  short *eA = sA[2], *eB = sB[2];

  for (int t = 0; t < NIT; ++t) {
    if (t + 2 < NIT) STAGE_P1((t+2)*64, eA, eB);

    s16x8 af[4][2], bf[2][2];
#pragma unroll
    for (int mt = 0; mt < 4; mt++)
#pragma unroll
      for (int kk = 0; kk < 2; kk++)
        af[mt][kk] = lds_frag(cA, offA[mt][kk]);
#pragma unroll
    for (int nt = 0; nt < 2; nt++)
#pragma unroll
      for (int kk = 0; kk < 2; kk++)
        bf[nt][kk] = lds_frag(cB, offB[nt][kk]);
    __builtin_amdgcn_s_setprio(1);
#pragma unroll
    for (int kk = 0; kk < 2; kk++)
#pragma unroll
      for (int mt = 0; mt < 4; mt++) {
        acc[mt][0] = __builtin_amdgcn_mfma_f32_16x16x32_bf16(af[mt][kk], bf[0][kk], acc[mt][0], 0, 0, 0);
        acc[mt][1] = __builtin_amdgcn_mfma_f32_16x16x32_bf16(af[mt][kk], bf[1][kk], acc[mt][1], 0, 0, 0);
      }
    __builtin_amdgcn_s_setprio(0);
    SCHEDB;
    BAR;

    if (t + 2 < NIT) STAGE_P2((t+2)*64, eB);
#pragma unroll
    for (int nt = 0; nt < 2; nt++)
#pragma unroll
      for (int kk = 0; kk < 2; kk++)
        bf[nt][kk] = lds_frag(cB, offB[nt+2][kk]);
    __builtin_amdgcn_s_setprio(1);
#pragma unroll
    for (int kk = 0; kk < 2; kk++)
#pragma unroll
      for (int mt = 0; mt < 4; mt++) {
        acc[mt][2] = __builtin_amdgcn_mfma_f32_16x16x32_bf16(af[mt][kk], bf[0][kk], acc[mt][2], 0, 0, 0);
        acc[mt][3] = __builtin_amdgcn_mfma_f32_16x16x32_bf16(af[mt][kk], bf[1][kk], acc[mt][3], 0, 0, 0);
      }
    __builtin_amdgcn_s_setprio(0);
    SCHEDB;
    if (t + 2 < NIT)      { WAITV(6); }
    else if (t + 1 < NIT) { WAITV(0); }
    BAR;

    const short *tAp = cA, *tBp = cB;
    cA = nA; cB = nB;
    nA = eA; nB = eB;
    eA = (short*)tAp; eB = (short*)tBp;
  }

  const int gm0 = bm*128 + m_off;
  const int gn0 = bn*256 + n_off;
#pragma unroll
  for (int mt = 0; mt < 4; mt++)
#pragma unroll
    for (int nt = 0; nt < 4; nt++) {
      int col = gn0 + nt*16 + lr;
#pragma unroll
      for (int r = 0; r < 4; r++) {
        int row = gm0 + mt*16 + lq*4 + r;
        Cf[(size_t)row * Ndim + col] = acc[mt][nt][r];
      }
    }
}

// ---------------- flash-style causal attention (R12 anchor, verbatim) -----
#define PPITCH 72   // 64 keys + 8 pad; 2-way banks (free)

static __device__ __forceinline__ void attn_stage(
    const short* __restrict__ Kp, const short* __restrict__ Vp, int kbase,
    short* __restrict__ sK, short* __restrict__ sV,
    int c0, int r0, int g0, int c1, int r1, int g1)
{
  GLDS16(Kp + (size_t)(kbase + r0)*Dh + g0, sK + c0*8);
  GLDS16(Kp + (size_t)(kbase + r1)*Dh + g1, sK + c1*8);
  GLDS16(Vp + (size_t)r0*Tsz + kbase + g0, sV + c0*8);
  GLDS16(Vp + (size_t)r1*Tsz + kbase + g1, sV + c1*8);
}

static __device__ __forceinline__ void attn_compute(
    const short* __restrict__ sK, const short* __restrict__ sV,
    int kbase, int q0, int lr, int lq, int sw,
    short* __restrict__ pb, const s16x8 bq[2][2], fx4 o[2][4], float li[2])
{
  const float sc = 0.125f * 1.44269504f;   // 1/sqrt(64) * log2(e)
  const bool masked = (kbase + 63 > q0);   // wave-uniform

  fx4 s[2][4];
#pragma unroll
  for (int j = 0; j < 2; j++)
#pragma unroll
    for (int mt = 0; mt < 4; mt++) s[j][mt] = (fx4){0.f,0.f,0.f,0.f};
  __builtin_amdgcn_s_setprio(1);
#pragma unroll
  for (int mt = 0; mt < 4; mt++)
#pragma unroll
    for (int kk = 0; kk < 2; kk++) {
      const s16x8 akf = *(const s16x8*)(sK + (mt*16 + lr)*64 + ((kk*4 + lq) ^ sw)*8);
      s[0][mt] = __builtin_amdgcn_mfma_f32_16x16x32_bf16(akf, bq[0][kk], s[0][mt], 0, 0, 0);
      s[1][mt] = __builtin_amdgcn_mfma_f32_16x16x32_bf16(akf, bq[1][kk], s[1][mt], 0, 0, 0);
    }
  __builtin_amdgcn_s_setprio(0);

#pragma unroll
  for (int j = 0; j < 2; j++) {
    const int qg = q0 + 16*j + lr;
    float p[16];
#pragma unroll
    for (int mt = 0; mt < 4; mt++)
#pragma unroll
      for (int r = 0; r < 4; r++) {
        float v = s[j][mt][r];
        if (masked) {
          int jg = kbase + mt*16 + lq*4 + r;
          v = (jg <= qg) ? v : -1e30f;
        }
        p[mt*4 + r] = __builtin_amdgcn_exp2f(v * sc);
      }
    float s8[8];
#pragma unroll
    for (int i = 0; i < 8; i++) s8[i] = p[i] + p[i+8];
    float s4[4];
#pragma unroll
    for (int i = 0; i < 4; i++) s4[i] = s8[i] + s8[i+4];
    li[j] += (s4[0] + s4[2]) + (s4[1] + s4[3]);
#pragma unroll
    for (int mt = 0; mt < 4; mt++) {
      s16x4 pk;
      pk.x = f2bf(p[mt*4+0]); pk.y = f2bf(p[mt*4+1]);
      pk.z = f2bf(p[mt*4+2]); pk.w = f2bf(p[mt*4+3]);
      *(s16x4*)(pb + (16*j + lr)*PPITCH + mt*16 + lq*4) = pk;
    }
  }
  __asm__ __volatile__("" ::: "memory");
  s16x8 pf[2][2];
#pragma unroll
  for (int j = 0; j < 2; j++)
#pragma unroll
    for (int kk = 0; kk < 2; kk++)
      pf[j][kk] = *(const s16x8*)(pb + (16*j + lr)*PPITCH + kk*32 + lq*8);
  __asm__ __volatile__("" ::: "memory");

  __builtin_amdgcn_s_setprio(1);
#pragma unroll
  for (int dt = 0; dt < 4; dt++)
#pragma unroll
    for (int kk = 0; kk < 2; kk++) {
      const s16x8 avf = *(const s16x8*)(sV + (dt*16 + lr)*64 + ((kk*4 + lq) ^ sw)*8);
      o[0][dt] = __builtin_amdgcn_mfma_f32_16x16x32_bf16(avf, pf[0][kk], o[0][dt], 0, 0, 0);
      o[1][dt] = __builtin_amdgcn_mfma_f32_16x16x32_bf16(avf, pf[1][kk], o[1][dt], 0, 0, 0);
    }
  __builtin_amdgcn_s_setprio(0);
}

__global__ __launch_bounds__(256) void attn_kernel(
    const short* __restrict__ Qb, const short* __restrict__ Kb,
    const short* __restrict__ Vt, short* __restrict__ Y)
{
  __shared__ __align__(16) short sK[2][64*64];     // 2 x 8 KB
  __shared__ __align__(16) short sV[2][64*64];     // 2 x 8 KB
  __shared__ __align__(16) short pbuf[4][32*PPITCH];
  const int tid  = threadIdx.x;
  const int lane = tid & 63;
  const int wv   = tid >> 6;
  const int lr   = lane & 15;
  const int lq   = lane >> 4;
  const int sw   = lr & 7;
  const int bh   = blockIdx.x;
  const int qb   = 15 - (int)blockIdx.y;   // heavy blocks first
  const int b    = bh >> 4;
  const int h    = bh & 15;
  const int q0   = qb*128 + wv*32;         // wave covers q0..q0+31

  const short* Qp = Qb + (size_t)bh * Tsz * Dh;
  const short* Kp = Kb + (size_t)bh * Tsz * Dh;
  const short* Vp = Vt + (size_t)bh * Dh * Tsz;
  short* pb = pbuf[wv];

  const int c0 = tid,       r0 = c0 >> 3, g0 = (((c0 & 7) ^ (r0 & 7)) * 8);
  const int c1 = tid + 256, r1 = c1 >> 3, g1 = (((c1 & 7) ^ (r1 & 7)) * 8);

  s16x8 bq[2][2];
#pragma unroll
  for (int j = 0; j < 2; j++)
#pragma unroll
    for (int kk = 0; kk < 2; kk++)
      bq[j][kk] = *(const s16x8*)(Qp + (size_t)(q0 + 16*j + lr)*Dh + kk*32 + lq*8);

  fx4 o[2][4];
#pragma unroll
  for (int j = 0; j < 2; j++)
#pragma unroll
    for (int i = 0; i < 4; i++) o[j][i] = (fx4){0.f, 0.f, 0.f, 0.f};
  float li[2] = {0.f, 0.f};

  const int ntiles = 2*qb + 2;             // even; keys 0 .. qb*128+127
  attn_stage(Kp, Vp, 0, sK[0], sV[0], c0, r0, g0, c1, r1, g1);
  for (int kt = 0; kt < ntiles; kt += 2) {
    __syncthreads();
    if (kt + 1 < ntiles) attn_stage(Kp, Vp, (kt+1)*64, sK[1], sV[1], c0, r0, g0, c1, r1, g1);
    if (kt*64 <= q0 + 31)
      attn_compute(sK[0], sV[0], kt*64, q0, lr, lq, sw, pb, bq, o, li);
    __syncthreads();
    if (kt + 2 < ntiles) attn_stage(Kp, Vp, (kt+2)*64, sK[0], sV[0], c0, r0, g0, c1, r1, g1);
    if ((kt+1)*64 <= q0 + 31)
      attn_compute(sK[1], sV[1], (kt+1)*64, q0, lr, lq, sw, pb, bq, o, li);
  }

#pragma unroll
  for (int j = 0; j < 2; j++) {
    float l = li[j];
    l += __shfl_xor(l, 16);
    l += __shfl_xor(l, 32);
    float inv = 1.0f / l;
#pragma unroll
    for (int dt = 0; dt < 4; dt++) {
      s16x4 yk;
      yk.x = f2bf(o[j][dt][0]*inv); yk.y = f2bf(o[j][dt][1]*inv);
      yk.z = f2bf(o[j][dt][2]*inv); yk.w = f2bf(o[j][dt][3]*inv);
      *(s16x4*)(Y + ((size_t)b*Tsz + q0 + 16*j + lr)*Csz + h*Dh + dt*16 + lq*4) = yk;
    }
  }
}

// ---------------- launcher (4 dispatches) ----------------
extern "C" void kernel_launch(void* const* d_in, const int* in_sizes, int n_in,
                              void* d_out, int out_size, void* d_ws, size_t ws_size,
                              hipStream_t stream)
{
  const float* x  = (const float*)d_in[0];
  const float* wq = (const float*)d_in[1];   // (C, 3C)
  const float* wp = (const float*)d_in[2];   // (C, C)
  float* out = (float*)d_out;

  char* ws = (char*)d_ws;
  size_t off = 0;
  short* xb  = (short*)(ws + off); off += (size_t)Mrows*Csz*2;
  short* wqT = (short*)(ws + off); off += (size_t)N1*Csz*2;
  short* wpT = (short*)(ws + off); off += (size_t)Csz*Csz*2;
  short* Qb  = (short*)(ws + off); off += (size_t)BH*Tsz*Dh*2;
  short* Kb  = (short*)(ws + off); off += (size_t)BH*Tsz*Dh*2;
  short* Vt  = (short*)(ws + off); off += (size_t)BH*Dh*Tsz*2;
  short* Yb  = (short*)(ws + off); off += (size_t)Mrows*Csz*2;

  prep_kernel<<<1024 + 3072 + 1024, 256, 0, stream>>>(x, xb, wq, wqT, wp, wpT);
  gemm_qkv_kernel<<<(Mrows/256)*(N1/256), 512, 0, stream>>>(
      xb, wqT, Qb, Kb, Vt, N1, Csz);
  attn_kernel<<<dim3(BH, Tsz/128), 256, 0, stream>>>(Qb, Kb, Vt, Yb);
  gemm_bt_kernel<<<(Mrows/128)*(Csz/256), 512, 0, stream>>>(
      Yb, wpT, out, Mrows, Csz, Csz);
}

// Round 10
// 245.948 us; speedup vs baseline: 1.0124x; 1.0124x over previous
//
#include <hip/hip_runtime.h>
#include <hip/hip_bf16.h>
#include <stdint.h>

// Problem constants
#define Bsz 4
#define Tsz 2048
#define Csz 1024
#define Hn  16
#define Dh  64
#define BH  (Bsz*Hn)      // 64
#define Mrows (Bsz*Tsz)   // 8192
#define N1  (3*Csz)       // 3072

typedef short s16x8 __attribute__((ext_vector_type(8)));
typedef short s16x4 __attribute__((ext_vector_type(4)));
typedef float fx4   __attribute__((ext_vector_type(4)));

static __device__ __forceinline__ short f2bf(float x) {
  __hip_bfloat16 h = __float2bfloat16(x);   // RNE
  return __builtin_bit_cast(short, h);
}

#define GLDS16(g, l) __builtin_amdgcn_global_load_lds( \
    (const __attribute__((address_space(1))) void*)(g), \
    (__attribute__((address_space(3))) void*)(l), 16, 0, 0)

#define WAITV(n) __asm__ __volatile__("s_waitcnt vmcnt(" #n ")" ::: "memory")
#define SCHEDB   __builtin_amdgcn_sched_barrier(0)
#define BAR      __builtin_amdgcn_s_barrier()

// ---------- fused prep: f32->bf16 cvt + two weight transposes -------------
__global__ __launch_bounds__(256) void prep_kernel(
    const float* __restrict__ x,  short* __restrict__ xb,
    const float* __restrict__ wq, short* __restrict__ wqT,
    const float* __restrict__ wp, short* __restrict__ wpT)
{
  const int bid = (int)blockIdx.x;
  if (bid < 1024) {
    const int n4 = Mrows*Csz/4;
    int i = bid * 256 + threadIdx.x;
    const int stride = 1024 * 256;
    for (; i < n4; i += stride) {
      float4 v = ((const float4*)x)[i];
      s16x4 o;
      o.x = f2bf(v.x); o.y = f2bf(v.y); o.z = f2bf(v.z); o.w = f2bf(v.w);
      ((s16x4*)xb)[i] = o;
    }
    return;
  }
  const float* w; short* wt; int K, N, tb;
  if (bid < 1024 + 3072) { w = wq; wt = wqT; K = Csz; N = N1;  tb = bid - 1024; }
  else                   { w = wp; wt = wpT; K = Csz; N = Csz; tb = bid - 4096; }
  const int nbx = N >> 5;
  const int n0 = (tb % nbx) * 32;
  const int k0 = (tb / nbx) * 32;
  __shared__ float tile[32][33];
  int tc = threadIdx.x & 31;
  int tr = threadIdx.x >> 5;      // 0..7
#pragma unroll
  for (int p = 0; p < 4; p++) {
    int r = tr + p*8;
    tile[r][tc] = w[(size_t)(k0 + r) * N + (n0 + tc)];
  }
  __syncthreads();
#pragma unroll
  for (int p = 0; p < 4; p++) {
    int r = tr + p*8;   // output (n) row
    wt[(size_t)(n0 + r) * K + (k0 + tc)] = f2bf(tile[tc][r]);
  }
}

// ---------------- bf16 MFMA GEMM: C = A * Bt^T (R12 anchor, verbatim) -----
// 128x256 tile, BK=64, 512 thr = 8 waves (2x4), 3-deep LDS (144 KB),
// counted vmcnt(6), XCD-contiguous bijective block swizzle, stage split 3+3.
// R15 post-mortem: 8-phase port measured 84 µs vs this kernel's 80 — the
// phased schedule does not transfer to this config; keep the 2-phase anchor.
static __device__ __forceinline__ s16x8 lds_frag(const short* p, int off) {
  return *(const s16x8*)(p + off);
}

__global__ __launch_bounds__(512) void gemm_bt_kernel(
    const short* __restrict__ A, const short* __restrict__ Bt,
    float* __restrict__ Cf,
    short* __restrict__ Qo, short* __restrict__ Ko, short* __restrict__ Vo,
    int Mdim, int Ndim, int Kdim, int mode)
{
  __shared__ __align__(16) short sA[3][128*64];   // 3 x 16 KB
  __shared__ __align__(16) short sB[3][256*64];   // 3 x 32 KB
  const int tid  = threadIdx.x;
  const int lane = tid & 63;
  const int lr   = lane & 15;
  const int lq   = lane >> 4;
  const int wv   = tid >> 6;               // 0..7
  const int nb   = Ndim >> 8;              // 256-wide n tiles
  const int nwg  = (int)gridDim.x;
  const int orig = (int)blockIdx.x;
  const int wgid = (orig & 7) * (nwg >> 3) + (orig >> 3);
  const int bm   = wgid / nb;
  const int bn   = wgid % nb;
  const int m_off = (wv & 1) << 6;         // 0 / 64
  const int n_off = (wv >> 1) << 6;        // 0 / 64 / 128 / 192

  const short* Ab = A  + (size_t)bm * 128 * Kdim;
  const short* Bb = Bt + (size_t)bn * 256 * Kdim;

  const short* gA[2];
  const short* gB[4];
#pragma unroll
  for (int j = 0; j < 2; j++) {
    int c = tid + 512*j, r = c >> 3, o = ((c & 7) ^ (r & 7)) * 8;
    gA[j] = Ab + (size_t)r * Kdim + o;
  }
#pragma unroll
  for (int j = 0; j < 4; j++) {
    int c = tid + 512*j, r = c >> 3, o = ((c & 7) ^ (r & 7)) * 8;
    gB[j] = Bb + (size_t)r * Kdim + o;
  }

  int offA[4][2], offB[4][2];
#pragma unroll
  for (int ft = 0; ft < 4; ft++)
#pragma unroll
    for (int kk = 0; kk < 2; kk++) {
      int ra = m_off + ft*16 + lr;
      offA[ft][kk] = ra*64 + ((((kk<<2) | lq) ^ (ra & 7)) << 3);
      int rb = n_off + ft*16 + lr;
      offB[ft][kk] = rb*64 + ((((kk<<2) | lq) ^ (rb & 7)) << 3);
    }

  fx4 acc[4][4];
#pragma unroll
  for (int i = 0; i < 4; i++)
#pragma unroll
    for (int j = 0; j < 4; j++) acc[i][j] = (fx4){0.f, 0.f, 0.f, 0.f};

  auto STAGE_P1 = [&](int k0, short* dA, short* dB) {   // 3 loads
    GLDS16(gA[0] + k0, dA + tid*8);
    GLDS16(gA[1] + k0, dA + (tid+512)*8);
    GLDS16(gB[0] + k0, dB + tid*8);
  };
  auto STAGE_P2 = [&](int k0, short* dB) {              // 3 loads
    GLDS16(gB[1] + k0, dB + (tid+512)*8);
    GLDS16(gB[2] + k0, dB + (tid+1024)*8);
    GLDS16(gB[3] + k0, dB + (tid+1536)*8);
  };

  const int NIT = Kdim >> 6;   // K-tiles of 64 (16 for K=1024)

  STAGE_P1(0,  sA[0], sB[0]); STAGE_P2(0,  sB[0]);
  STAGE_P1(64, sA[1], sB[1]); STAGE_P2(64, sB[1]);
  WAITV(6);
  BAR;

  const short *cA = sA[0], *cB = sB[0];
  const short *nA = sA[1], *nB = sB[1];
  short *eA = sA[2], *eB = sB[2];

  for (int t = 0; t < NIT; ++t) {
    if (t + 2 < NIT) STAGE_P1((t+2)*64, eA, eB);

    // ---- phase 1: n-frags 0,1 ----
    s16x8 af[4][2], bf[2][2];
#pragma unroll
    for (int mt = 0; mt < 4; mt++)
#pragma unroll
      for (int kk = 0; kk < 2; kk++)
        af[mt][kk] = lds_frag(cA, offA[mt][kk]);
#pragma unroll
    for (int nt = 0; nt < 2; nt++)
#pragma unroll
      for (int kk = 0; kk < 2; kk++)
        bf[nt][kk] = lds_frag(cB, offB[nt][kk]);
    __builtin_amdgcn_s_setprio(1);
#pragma unroll
    for (int kk = 0; kk < 2; kk++)
#pragma unroll
      for (int mt = 0; mt < 4; mt++) {
        acc[mt][0] = __builtin_amdgcn_mfma_f32_16x16x32_bf16(af[mt][kk], bf[0][kk], acc[mt][0], 0, 0, 0);
        acc[mt][1] = __builtin_amdgcn_mfma_f32_16x16x32_bf16(af[mt][kk], bf[1][kk], acc[mt][1], 0, 0, 0);
      }
    __builtin_amdgcn_s_setprio(0);
    SCHEDB;
    BAR;

    // ---- phase 2: n-frags 2,3 ----
    if (t + 2 < NIT) STAGE_P2((t+2)*64, eB);
#pragma unroll
    for (int nt = 0; nt < 2; nt++)
#pragma unroll
      for (int kk = 0; kk < 2; kk++)
        bf[nt][kk] = lds_frag(cB, offB[nt+2][kk]);
    __builtin_amdgcn_s_setprio(1);
#pragma unroll
    for (int kk = 0; kk < 2; kk++)
#pragma unroll
      for (int mt = 0; mt < 4; mt++) {
        acc[mt][2] = __builtin_amdgcn_mfma_f32_16x16x32_bf16(af[mt][kk], bf[0][kk], acc[mt][2], 0, 0, 0);
        acc[mt][3] = __builtin_amdgcn_mfma_f32_16x16x32_bf16(af[mt][kk], bf[1][kk], acc[mt][3], 0, 0, 0);
      }
    __builtin_amdgcn_s_setprio(0);
    SCHEDB;
    if (t + 2 < NIT)      { WAITV(6); }
    else if (t + 1 < NIT) { WAITV(0); }
    BAR;

    const short *tAp = cA, *tBp = cB;
    cA = nA; cB = nB;
    nA = eA; nB = eB;
    eA = (short*)tAp; eB = (short*)tBp;
  }

  const int gm0 = bm*128 + m_off;
  const int gn0 = bn*256 + n_off;
  if (mode == 0) {
#pragma unroll
    for (int mt = 0; mt < 4; mt++)
#pragma unroll
      for (int nt = 0; nt < 4; nt++) {
        int col = gn0 + nt*16 + lr;
#pragma unroll
        for (int r = 0; r < 4; r++) {
          int row = gm0 + mt*16 + lq*4 + r;
          Cf[(size_t)row * Ndim + col] = acc[mt][nt][r];
        }
      }
  } else {
#pragma unroll
    for (int mt = 0; mt < 4; mt++)
#pragma unroll
      for (int nt = 0; nt < 4; nt++) {
        int n   = gn0 + nt*16 + lr;
        int sec = n >> 10;        // 0=q 1=k 2=v (wave-uniform per nt)
        int cc  = n & 1023;
        int hh  = cc >> 6;
        int dd  = cc & 63;
        if (sec == 2) {
          int tt0 = gm0 + mt*16 + lq*4;
          int bb  = tt0 >> 11;
          int bh  = bb * Hn + hh;
          s16x4 pk;
          pk.x = f2bf(acc[mt][nt][0]); pk.y = f2bf(acc[mt][nt][1]);
          pk.z = f2bf(acc[mt][nt][2]); pk.w = f2bf(acc[mt][nt][3]);
          *(s16x4*)(Vo + ((size_t)bh * Dh + dd) * Tsz + (tt0 & 2047)) = pk;
        } else {
#pragma unroll
          for (int r = 0; r < 4; r++) {
            int m  = gm0 + mt*16 + lq*4 + r;
            int bb = m >> 11;
            int tt = m & 2047;
            int bh = bb * Hn + hh;
            short v = f2bf(acc[mt][nt][r]);
            if (sec == 0) Qo[((size_t)bh * Tsz + tt) * Dh + dd] = v;
            else          Ko[((size_t)bh * Tsz + tt) * Dh + dd] = v;
          }
        }
      }
  }
}

// ---------------- flash-style causal attention (R12 + XCD bh-locality) ----
// R16: attn is the 2nd-largest kernel (~75 µs by budget arithmetic; never in
// top-5 — all prior top-5 rows were QKV from the two rocprof passes). Its
// staged K/V traffic (278 MB) at the measured ~7 TB/s delivery rate is ~40 µs
// — delivery-bound like the GEMM, but with 16x REAL reuse: all 16 qb-blocks
// of one bh read the same 512 KB K/V. Old grid had bh varying fastest ->
// consecutive blocks (different bh) round-robined across XCDs -> K/V
// streamed from L3 repeatedly. New 1-D grid: XCD x owns bh in [8x, 8x+8)
// (bid&7 = XCD under round-robin dispatch); per-XCD K/V working set = 4 MB
// = L2 -> staged re-reads become L2 hits. Heavy-qb-first kept within XCD.
#define PPITCH 72   // 64 keys + 8 pad; 2-way banks (free)

static __device__ __forceinline__ void attn_stage(
    const short* __restrict__ Kp, const short* __restrict__ Vp, int kbase,
    short* __restrict__ sK, short* __restrict__ sV,
    int c0, int r0, int g0, int c1, int r1, int g1)
{
  GLDS16(Kp + (size_t)(kbase + r0)*Dh + g0, sK + c0*8);
  GLDS16(Kp + (size_t)(kbase + r1)*Dh + g1, sK + c1*8);
  GLDS16(Vp + (size_t)r0*Tsz + kbase + g0, sV + c0*8);
  GLDS16(Vp + (size_t)r1*Tsz + kbase + g1, sV + c1*8);
}

static __device__ __forceinline__ void attn_compute(
    const short* __restrict__ sK, const short* __restrict__ sV,
    int kbase, int q0, int lr, int lq, int sw,
    short* __restrict__ pb, const s16x8 bq[2][2], fx4 o[2][4], float li[2])
{
  const float sc = 0.125f * 1.44269504f;   // 1/sqrt(64) * log2(e)
  const bool masked = (kbase + 63 > q0);   // wave-uniform

  fx4 s[2][4];
#pragma unroll
  for (int j = 0; j < 2; j++)
#pragma unroll
    for (int mt = 0; mt < 4; mt++) s[j][mt] = (fx4){0.f,0.f,0.f,0.f};
  __builtin_amdgcn_s_setprio(1);
#pragma unroll
  for (int mt = 0; mt < 4; mt++)
#pragma unroll
    for (int kk = 0; kk < 2; kk++) {
      const s16x8 akf = *(const s16x8*)(sK + (mt*16 + lr)*64 + ((kk*4 + lq) ^ sw)*8);
      s[0][mt] = __builtin_amdgcn_mfma_f32_16x16x32_bf16(akf, bq[0][kk], s[0][mt], 0, 0, 0);
      s[1][mt] = __builtin_amdgcn_mfma_f32_16x16x32_bf16(akf, bq[1][kk], s[1][mt], 0, 0, 0);
    }
  __builtin_amdgcn_s_setprio(0);

#pragma unroll
  for (int j = 0; j < 2; j++) {
    const int qg = q0 + 16*j + lr;
    float p[16];
#pragma unroll
    for (int mt = 0; mt < 4; mt++)
#pragma unroll
      for (int r = 0; r < 4; r++) {
        float v = s[j][mt][r];
        if (masked) {
          int jg = kbase + mt*16 + lq*4 + r;
          v = (jg <= qg) ? v : -1e30f;
        }
        p[mt*4 + r] = __builtin_amdgcn_exp2f(v * sc);
      }
    float s8[8];
#pragma unroll
    for (int i = 0; i < 8; i++) s8[i] = p[i] + p[i+8];
    float s4[4];
#pragma unroll
    for (int i = 0; i < 4; i++) s4[i] = s8[i] + s8[i+4];
    li[j] += (s4[0] + s4[2]) + (s4[1] + s4[3]);
#pragma unroll
    for (int mt = 0; mt < 4; mt++) {
      s16x4 pk;
      pk.x = f2bf(p[mt*4+0]); pk.y = f2bf(p[mt*4+1]);
      pk.z = f2bf(p[mt*4+2]); pk.w = f2bf(p[mt*4+3]);
      *(s16x4*)(pb + (16*j + lr)*PPITCH + mt*16 + lq*4) = pk;
    }
  }
  __asm__ __volatile__("" ::: "memory");  // pin pbuf write->read (DS in-order/wave)
  s16x8 pf[2][2];
#pragma unroll
  for (int j = 0; j < 2; j++)
#pragma unroll
    for (int kk = 0; kk < 2; kk++)
      pf[j][kk] = *(const s16x8*)(pb + (16*j + lr)*PPITCH + kk*32 + lq*8);
  __asm__ __volatile__("" ::: "memory");  // pin reads before next tile's writes

  __builtin_amdgcn_s_setprio(1);
#pragma unroll
  for (int dt = 0; dt < 4; dt++)
#pragma unroll
    for (int kk = 0; kk < 2; kk++) {
      const s16x8 avf = *(const s16x8*)(sV + (dt*16 + lr)*64 + ((kk*4 + lq) ^ sw)*8);
      o[0][dt] = __builtin_amdgcn_mfma_f32_16x16x32_bf16(avf, pf[0][kk], o[0][dt], 0, 0, 0);
      o[1][dt] = __builtin_amdgcn_mfma_f32_16x16x32_bf16(avf, pf[1][kk], o[1][dt], 0, 0, 0);
    }
  __builtin_amdgcn_s_setprio(0);
}

__global__ __launch_bounds__(256) void attn_kernel(
    const short* __restrict__ Qb, const short* __restrict__ Kb,
    const short* __restrict__ Vt, short* __restrict__ Y)
{
  __shared__ __align__(16) short sK[2][64*64];     // 2 x 8 KB
  __shared__ __align__(16) short sV[2][64*64];     // 2 x 8 KB
  __shared__ __align__(16) short pbuf[4][32*PPITCH];
  const int tid  = threadIdx.x;
  const int lane = tid & 63;
  const int wv   = tid >> 6;
  const int lr   = lane & 15;
  const int lq   = lane >> 4;
  const int sw   = lr & 7;
  // XCD-locality remap: bid&7 = XCD (round-robin dispatch); XCD x owns
  // bh in [8x, 8x+8) for all 16 qb -> per-XCD K/V working set 4 MB (= L2).
  // j&7 walks the 8 bh fastest; j>>3 walks qb heavy-first.
  const int bid  = (int)blockIdx.x;           // 0..1023
  const int j    = bid >> 3;                  // 0..127
  const int bh   = (bid & 7) * 8 + (j & 7);
  const int qb   = 15 - (j >> 3);             // heavy blocks first
  const int b    = bh >> 4;
  const int h    = bh & 15;
  const int q0   = qb*128 + wv*32;         // wave covers q0..q0+31

  const short* Qp = Qb + (size_t)bh * Tsz * Dh;
  const short* Kp = Kb + (size_t)bh * Tsz * Dh;
  const short* Vp = Vt + (size_t)bh * Dh * Tsz;
  short* pb = pbuf[wv];

  const int c0 = tid,       r0 = c0 >> 3, g0 = (((c0 & 7) ^ (r0 & 7)) * 8);
  const int c1 = tid + 256, r1 = c1 >> 3, g1 = (((c1 & 7) ^ (r1 & 7)) * 8);

  s16x8 bq[2][2];
#pragma unroll
  for (int jj = 0; jj < 2; jj++)
#pragma unroll
    for (int kk = 0; kk < 2; kk++)
      bq[jj][kk] = *(const s16x8*)(Qp + (size_t)(q0 + 16*jj + lr)*Dh + kk*32 + lq*8);

  fx4 o[2][4];
#pragma unroll
  for (int jj = 0; jj < 2; jj++)
#pragma unroll
    for (int i = 0; i < 4; i++) o[jj][i] = (fx4){0.f, 0.f, 0.f, 0.f};
  float li[2] = {0.f, 0.f};

  const int ntiles = 2*qb + 2;             // even; keys 0 .. qb*128+127
  attn_stage(Kp, Vp, 0, sK[0], sV[0], c0, r0, g0, c1, r1, g1);
  for (int kt = 0; kt < ntiles; kt += 2) {
    __syncthreads();
    if (kt + 1 < ntiles) attn_stage(Kp, Vp, (kt+1)*64, sK[1], sV[1], c0, r0, g0, c1, r1, g1);
    if (kt*64 <= q0 + 31)
      attn_compute(sK[0], sV[0], kt*64, q0, lr, lq, sw, pb, bq, o, li);
    __syncthreads();
    if (kt + 2 < ntiles) attn_stage(Kp, Vp, (kt+2)*64, sK[0], sV[0], c0, r0, g0, c1, r1, g1);
    if ((kt+1)*64 <= q0 + 31)
      attn_compute(sK[1], sV[1], (kt+1)*64, q0, lr, lq, sw, pb, bq, o, li);
  }

#pragma unroll
  for (int jj = 0; jj < 2; jj++) {
    float l = li[jj];
    l += __shfl_xor(l, 16);
    l += __shfl_xor(l, 32);
    float inv = 1.0f / l;
#pragma unroll
    for (int dt = 0; dt < 4; dt++) {
      s16x4 yk;
      yk.x = f2bf(o[jj][dt][0]*inv); yk.y = f2bf(o[jj][dt][1]*inv);
      yk.z = f2bf(o[jj][dt][2]*inv); yk.w = f2bf(o[jj][dt][3]*inv);
      *(s16x4*)(Y + ((size_t)b*Tsz + q0 + 16*jj + lr)*Csz + h*Dh + dt*16 + lq*4) = yk;
    }
  }
}

// ---------------- launcher (4 dispatches) ----------------
extern "C" void kernel_launch(void* const* d_in, const int* in_sizes, int n_in,
                              void* d_out, int out_size, void* d_ws, size_t ws_size,
                              hipStream_t stream)
{
  const float* x  = (const float*)d_in[0];
  const float* wq = (const float*)d_in[1];   // (C, 3C)
  const float* wp = (const float*)d_in[2];   // (C, C)
  float* out = (float*)d_out;

  char* ws = (char*)d_ws;
  size_t off = 0;
  short* xb  = (short*)(ws + off); off += (size_t)Mrows*Csz*2;
  short* wqT = (short*)(ws + off); off += (size_t)N1*Csz*2;
  short* wpT = (short*)(ws + off); off += (size_t)Csz*Csz*2;
  short* Qb  = (short*)(ws + off); off += (size_t)BH*Tsz*Dh*2;
  short* Kb  = (short*)(ws + off); off += (size_t)BH*Tsz*Dh*2;
  short* Vt  = (short*)(ws + off); off += (size_t)BH*Dh*Tsz*2;
  short* Yb  = (short*)(ws + off); off += (size_t)Mrows*Csz*2;

  prep_kernel<<<1024 + 3072 + 1024, 256, 0, stream>>>(x, xb, wq, wqT, wp, wpT);
  gemm_bt_kernel<<<(Mrows/128)*(N1/256), 512, 0, stream>>>(
      xb, wqT, nullptr, Qb, Kb, Vt, Mrows, N1, Csz, 1);
  attn_kernel<<<BH * (Tsz/128), 256, 0, stream>>>(Qb, Kb, Vt, Yb);
  gemm_bt_kernel<<<(Mrows/128)*(Csz/256), 512, 0, stream>>>(
      Yb, wpT, out, nullptr, nullptr, nullptr, Mrows, Csz, Csz, 0);
}